// Round 6
// baseline (346.272 us; speedup 1.0000x reference)
//
#include <hip/hip_runtime.h>

// MemoryBank contrastive loss, steady state.
// B=1024, D=128, C=50, K=4096, N = C*K = 204800. TEMP=0.3.
// loss = (1/B) * sum_b w_b * ( ln(sum exp(dot/T)) - dot_pos/T )
// SCALE = log2(e)/T folded into normalized bf16 features: MFMA acc feeds exp2.
//
// R6: single fused kernel + conflict-free LDS + occupancy.
//  - Frag-linear LDS: DMA global granules in exact fragment-read order
//    (slot = (nf*8+ks*2+h)*64+lane) -> frag reads are stride-1 b128,
//    conflict-free; swizzle cost is on the (free) per-lane global address.
//  - 32-row tiles, 16 KB, dbuf 32 KB -> 4 blocks/CU; VGPR<=128 (bounds 256,4)
//    -> 16 waves/CU, 4 independently-phased blocks per CU cover barriers.
//  - Feature normalization computed in-kernel (features L3-hot; redundant
//    per-block reads trivial). Finalize (pos logit + weighted mean) by the
//    LAST block via device-scope ticket; S re-read with atomicAdd(,0).

#define XCHUNK 256
#define NITER 25            // 256 * 25 = 6400 tiles of 32 rows = 204800
#define TILE_BYTES 16384    // 32 rows x 128 fp32
#define LN2f 0.6931471805599453f
#define SCALEf 4.808983469629878f   // log2(e)/0.3

typedef __attribute__((ext_vector_type(8))) short bf16x8;
typedef __attribute__((ext_vector_type(4))) float f32x4;
typedef unsigned int u32;

// two fp32 -> two bf16 (truncation) in one v_perm_b32: [bf(lo) | bf(hi)<<16]
__device__ __forceinline__ unsigned int pack_bf2(float lo, float hi) {
    union { float f; unsigned int u; } a, b; a.f = lo; b.f = hi;
    return __builtin_amdgcn_perm(b.u, a.u, 0x07060302u);
}
// async DMA global -> LDS, 16 B per lane; gp per-lane, lp wave-uniform base
__device__ __forceinline__ void gl_lds16(const void* gp, void* lp) {
    __builtin_amdgcn_global_load_lds(
        (const __attribute__((address_space(1))) u32*)gp,
        (__attribute__((address_space(3))) u32*)lp, 16, 0, 0);
}

__global__ __launch_bounds__(256, 4) void gemm_lse(
        const float* __restrict__ features,   // [1024][128] fp32
        const int*   __restrict__ labels,     // [1024]
        const float* __restrict__ mem,        // [204800][128] fp32
        float* __restrict__ S,                // [1024] exp2-sums (ws, zeroed)
        u32*   __restrict__ done,             // ticket counter (ws, zeroed)
        float* __restrict__ out)              // final loss
{
    __shared__ float ldsb[2][TILE_BYTES / 4];   // 2 x 16 KB, frag-linear order
    __shared__ u32 ticket_s;
    __shared__ float fin[4];

    const int tid  = threadIdx.x;
    const int wave = tid >> 6;        // 0..3
    const int lane = tid & 63;
    const int col  = lane & 15;
    const int quad = lane >> 4;

    const int m_base = blockIdx.y * 256 + wave * 64;
    const int xc = blockIdx.x;        // 0..255

    // ---- in-kernel feature normalization -> A-frags (A[m=col][k=quad*8+j]) ----
    bf16x8 afrag[4][4];
    #pragma unroll
    for (int mf = 0; mf < 4; ++mf) {
        const float4* frow = (const float4*)(features + (size_t)(m_base + mf * 16 + col) * 128);
        float4 v[8];
        #pragma unroll
        for (int ks = 0; ks < 4; ++ks) {
            v[2 * ks]     = frow[ks * 8 + quad * 2];
            v[2 * ks + 1] = frow[ks * 8 + quad * 2 + 1];
        }
        float ss = 0.0f;
        #pragma unroll
        for (int i = 0; i < 8; ++i)
            ss += v[i].x * v[i].x + v[i].y * v[i].y + v[i].z * v[i].z + v[i].w * v[i].w;
        ss += __shfl_xor(ss, 16, 64);     // reduce across quads (same col)
        ss += __shfl_xor(ss, 32, 64);
        float inv = SCALEf / fmaxf(sqrtf(ss), 1e-12f);
        #pragma unroll
        for (int ks = 0; ks < 4; ++ks) {
            uint4 pk;
            pk.x = pack_bf2(v[2*ks].x   * inv, v[2*ks].y   * inv);
            pk.y = pack_bf2(v[2*ks].z   * inv, v[2*ks].w   * inv);
            pk.z = pack_bf2(v[2*ks+1].x * inv, v[2*ks+1].y * inv);
            pk.w = pack_bf2(v[2*ks+1].z * inv, v[2*ks+1].w * inv);
            afrag[mf][ks] = *(bf16x8*)&pk;
        }
    }

    float s_part[16];
    #pragma unroll
    for (int i = 0; i < 16; ++i) s_part[i] = 0.0f;

    // DMA offsets: issue i stages slots [i*256+tid]; code = i*4+wave in 0..15
    // decodes (nf,ks,h); global granule = row (nf*16+col), k-gran ks*8+quad*2+h
    int goffb[4];
    #pragma unroll
    for (int i = 0; i < 4; ++i) {
        int code = i * 4 + wave;
        int h  = code & 1;
        int ks = (code >> 1) & 3;
        int nf = (code >> 3) & 1;
        goffb[i] = (nf * 16 + col) * 512 + ks * 128 + quad * 32 + h * 16;
    }

    #define STAGE(bi, t_) {                                                     \
        const char* gt = (const char*)mem + (size_t)(xc + XCHUNK * (t_)) * TILE_BYTES; \
        _Pragma("unroll")                                                       \
        for (int i = 0; i < 4; ++i)                                             \
            gl_lds16(gt + goffb[i], (char*)&ldsb[bi][0] + (i * 4096 + wave * 1024)); }

    #define COMPUTE(bi) {                                                       \
        const char* buf = (const char*)&ldsb[bi][0];                            \
        _Pragma("unroll")                                                       \
        for (int nf = 0; nf < 2; ++nf) {                                        \
            bf16x8 bfrag[4];                                                    \
            _Pragma("unroll")                                                   \
            for (int ks = 0; ks < 4; ++ks) {                                    \
                const char* p = buf + (nf * 8 + ks * 2) * 1024 + lane * 16;     \
                float4 f0 = *(const float4*)p;                                  \
                float4 f1 = *(const float4*)(p + 1024);                         \
                uint4 pk;                                                       \
                pk.x = pack_bf2(f0.x, f0.y); pk.y = pack_bf2(f0.z, f0.w);       \
                pk.z = pack_bf2(f1.x, f1.y); pk.w = pack_bf2(f1.z, f1.w);       \
                bfrag[ks] = *(bf16x8*)&pk;                                      \
            }                                                                   \
            f32x4 acc[4];                                                       \
            _Pragma("unroll")                                                   \
            for (int mf = 0; mf < 4; ++mf) acc[mf] = (f32x4)(0.0f);             \
            _Pragma("unroll")                                                   \
            for (int ks = 0; ks < 4; ++ks)                                      \
                _Pragma("unroll")                                               \
                for (int mf = 0; mf < 4; ++mf)                                  \
                    acc[mf] = __builtin_amdgcn_mfma_f32_16x16x32_bf16(          \
                        afrag[mf][ks], bfrag[ks], acc[mf], 0, 0, 0);            \
            _Pragma("unroll")                                                   \
            for (int mf = 0; mf < 4; ++mf)                                      \
                _Pragma("unroll")                                               \
                for (int r = 0; r < 4; ++r)                                     \
                    s_part[mf * 4 + r] += __builtin_amdgcn_exp2f(acc[mf][r]);   \
        } }

    STAGE(0, 0)
    __syncthreads();

    for (int t = 0; t < NITER; ++t) {
        if (t + 1 < NITER) STAGE((t + 1) & 1, t + 1)
        COMPUTE(t & 1)
        __syncthreads();
    }

    // reduce across the 16 col-lanes sharing the same quad; add to S
    #pragma unroll
    for (int d = 1; d < 16; d <<= 1)
        #pragma unroll
        for (int i = 0; i < 16; ++i)
            s_part[i] += __shfl_xor(s_part[i], d, 64);

    if (col == 0) {
        #pragma unroll
        for (int i = 0; i < 16; ++i) {
            int row = m_base + (i >> 2) * 16 + quad * 4 + (i & 3);
            atomicAdd(&S[row], s_part[i]);
        }
    }

    // ---- last-block finalize ----
    __threadfence();                       // S atomics visible device-wide
    __syncthreads();
    if (tid == 0) ticket_s = atomicAdd(done, 1u);
    __syncthreads();
    if (ticket_s == 256u * 4u - 1u) {
        float local = 0.0f;
        #pragma unroll
        for (int s = 0; s < 4; ++s) {
            int b = s * 256 + tid;
            int lab = labels[b];
            const float4* f4 = (const float4*)(features + (size_t)b * 128);
            const float4* m4 = (const float4*)(mem + (size_t)lab * (4096 * 128));
            float ss = 0.0f, dt = 0.0f;
            #pragma unroll 8
            for (int j = 0; j < 32; ++j) {
                float4 fv = f4[j], mv = m4[j];
                ss += fv.x * fv.x + fv.y * fv.y + fv.z * fv.z + fv.w * fv.w;
                dt += fv.x * mv.x + fv.y * mv.y + fv.z * mv.z + fv.w * mv.w;
            }
            float tpos = SCALEf * dt / fmaxf(sqrtf(ss), 1e-12f);
            float Sb = atomicAdd(&S[b], 0.0f);          // coherent read-back
            float w = (lab < 2) ? 1.3f : 1.0f;
            local += w * (log2f(Sb) - tpos);
        }
        #pragma unroll
        for (int d = 1; d < 64; d <<= 1) local += __shfl_xor(local, d, 64);
        if (lane == 0) fin[wave] = local;
        __syncthreads();
        if (tid == 0)
            *out = (fin[0] + fin[1] + fin[2] + fin[3]) * (LN2f / 1024.0f);
    }
    #undef STAGE
    #undef COMPUTE
}

extern "C" void kernel_launch(void* const* d_in, const int* in_sizes, int n_in,
                              void* d_out, int out_size, void* d_ws, size_t ws_size,
                              hipStream_t stream) {
    const float* features = (const float*)d_in[0];
    const int*   labels   = (const int*)d_in[1];
    const float* memory   = (const float*)d_in[2];
    float* out = (float*)d_out;

    float* S   = (float*)d_ws;                       // 1024 floats
    u32*  done = (u32*)((char*)d_ws + 4096);         // ticket counter

    hipMemsetAsync(d_ws, 0, 4096 + sizeof(u32), stream);
    gemm_lse<<<dim3(XCHUNK, 4), 256, 0, stream>>>(features, labels, memory,
                                                  S, done, out);
}

// Round 7
// 262.248 us; speedup vs baseline: 1.3204x; 1.3204x over previous
//
#include <hip/hip_runtime.h>

// MemoryBank contrastive loss, steady state.
// B=1024, D=128, C=50, K=4096, N = C*K = 204800. TEMP=0.3.
// loss = (1/B) * sum_b w_b * ( ln(sum exp(dot/T)) - dot_pos/T )
// SCALE = log2(e)/T folded into normalized bf16 features: MFMA acc feeds exp2.
//
// R7: barrier-free wave-private GEMM.
//  - Each WAVE is an independent worker: owns 128 m-rows (afrag 128 VGPR,
//    launch_bounds(256,2) -> 256-reg budget, ~225 peak, no spill), streams
//    16-row n-chunks (8 KB fp32) through a PRIVATE LDS double-buffer.
//  - global_load_lds DMA in frag-linear order (R6-proven conflict-free);
//    no __syncthreads in the K-loop at all -- DMA tracked by wave-local
//    vmcnt; per-iteration order read(cur) -> stage(cur<-t+2) -> mfma/exp2
//    gives one full compute phase of prefetch distance.
//  - m-replication 16x -> 8x: LDS traffic 26 us/CU ~= MFMA 26 us, overlapped.
//  - Grid (64,8): 512 blocks = 2/CU; 256 n-workers sweep the same 2 MB
//    window simultaneously (chunk = nw + 256*t) -> L2/L3 dedup of 8x fetch.

#define LN2f 0.6931471805599453f
#define SCALEf 4.808983469629878f   // log2(e)/0.3
#define NCHUNKS 50                  // per worker: 50 * 256 workers * 16 rows = 204800

typedef __attribute__((ext_vector_type(8))) short bf16x8;
typedef __attribute__((ext_vector_type(4))) float f32x4;
typedef unsigned int u32;

__device__ __forceinline__ unsigned short f2bf(float x) {
    union { float f; unsigned int u; } c; c.f = x;
    unsigned int u = c.u;
    u = (u + 0x7fffu + ((u >> 16) & 1u)) >> 16;   // RNE (features only)
    return (unsigned short)u;
}
__device__ __forceinline__ float bf2f(unsigned short h) {
    union { unsigned int u; float f; } c; c.u = ((unsigned int)h) << 16;
    return c.f;
}
// two fp32 -> two bf16 (truncation) in one v_perm_b32: [bf(lo) | bf(hi)<<16]
__device__ __forceinline__ unsigned int pack_bf2(float lo, float hi) {
    union { float f; unsigned int u; } a, b; a.f = lo; b.f = hi;
    return __builtin_amdgcn_perm(b.u, a.u, 0x07060302u);
}
// async DMA global -> LDS, 16 B per lane; gp per-lane, lp wave-uniform base
__device__ __forceinline__ void gl_lds16(const void* gp, void* lp) {
    __builtin_amdgcn_global_load_lds(
        (const __attribute__((address_space(1))) u32*)gp,
        (__attribute__((address_space(3))) u32*)lp, 16, 0, 0);
}

// ---- Kernel 1: normalize+scale features -> bf16; zero S and out -------------
__global__ void normalize_feat(const float* __restrict__ f,
                               unsigned short* __restrict__ featb,
                               float* __restrict__ S,
                               float* __restrict__ out) {
    const int b = blockIdx.x;          // 1024 blocks
    const int t = threadIdx.x;         // 128 threads
    if (t == 0) S[b] = 0.0f;
    if (b == 0 && t == 1) *out = 0.0f;
    float v = f[b * 128 + t];
    float ss = v * v;
    #pragma unroll
    for (int m = 1; m < 64; m <<= 1) ss += __shfl_xor(ss, m, 64);
    __shared__ float wsum[2];
    if ((t & 63) == 0) wsum[t >> 6] = ss;
    __syncthreads();
    float tot = wsum[0] + wsum[1];
    float inv = SCALEf / fmaxf(sqrtf(tot), 1e-12f);
    featb[b * 128 + t] = f2bf(v * inv);
}

// ---- Kernel 2: fused GEMM + exp2-sum, barrier-free --------------------------
__global__ __launch_bounds__(256, 2) void gemm_lse(
        const unsigned short* __restrict__ featb,  // [1024][128] bf16 (scaled)
        const float* __restrict__ mem,             // [204800][128] fp32
        float* __restrict__ S)                     // [1024] exp2-sums
{
    // per-wave private double buffer: [wave][buf][16 rows x 128 fp32 = 8 KB]
    __shared__ float ldsb[4][2][2048];

    const int tid  = threadIdx.x;
    const int wave = tid >> 6;
    const int lane = tid & 63;
    const int col  = lane & 15;
    const int quad = lane >> 4;

    const int mg = blockIdx.y;                     // m-group 0..7 (128 rows)
    const int nw = blockIdx.x * 4 + wave;          // n-worker 0..255

    // A fragments: A[m=col][k=quad*8+j], mf=8 x ks=4 (128 VGPR)
    bf16x8 afrag[8][4];
    #pragma unroll
    for (int mf = 0; mf < 8; ++mf)
        #pragma unroll
        for (int ks = 0; ks < 4; ++ks)
            afrag[mf][ks] = *(const bf16x8*)&featb[(size_t)(mg * 128 + mf * 16 + col) * 128
                                                   + ks * 32 + quad * 8];

    float s_part[32];
    #pragma unroll
    for (int i = 0; i < 32; ++i) s_part[i] = 0.0f;

    // frag-linear DMA: LDS slot (i*64+lane) <- global granule
    //   row n = lane&15, k-granule = (i>>1)*8 + (lane>>4)*2 + (i&1)
    const int gbase = (lane & 15) * 512 + (lane >> 4) * 32;   // bytes in chunk
    const char* memb = (const char*)mem;

    #define STAGE(bi, t_) {                                                     \
        const char* gt = memb + (size_t)(nw + 256 * (t_)) * 8192;               \
        char* lb = (char*)&ldsb[wave][bi][0];                                   \
        _Pragma("unroll")                                                       \
        for (int i = 0; i < 8; ++i)                                             \
            gl_lds16(gt + gbase + (i >> 1) * 128 + (i & 1) * 16, lb + i * 1024); }

    STAGE(0, 0)
    STAGE(1, 1)

    for (int t = 0; t < NCHUNKS; ++t) {
        const int bi = t & 1;
        const float* buf = &ldsb[wave][bi][0];

        // read + pack the wave's chunk (stride-1 lane-consecutive, 0 conflicts)
        bf16x8 bfrag[4];
        #pragma unroll
        for (int ks = 0; ks < 4; ++ks) {
            float4 f0 = *(const float4*)&buf[(ks * 2)     * 256 + lane * 4];
            float4 f1 = *(const float4*)&buf[(ks * 2 + 1) * 256 + lane * 4];
            uint4 pk;
            pk.x = pack_bf2(f0.x, f0.y); pk.y = pack_bf2(f0.z, f0.w);
            pk.z = pack_bf2(f1.x, f1.y); pk.w = pack_bf2(f1.z, f1.w);
            bfrag[ks] = *(bf16x8*)&pk;
        }

        // refill this buffer for t+2 (reads above already consumed)
        if (t + 2 < NCHUNKS) STAGE(bi, t + 2)

        f32x4 acc[8];
        #pragma unroll
        for (int mf = 0; mf < 8; ++mf) acc[mf] = (f32x4)(0.0f);
        #pragma unroll
        for (int ks = 0; ks < 4; ++ks)
            #pragma unroll
            for (int mf = 0; mf < 8; ++mf)
                acc[mf] = __builtin_amdgcn_mfma_f32_16x16x32_bf16(
                    afrag[mf][ks], bfrag[ks], acc[mf], 0, 0, 0);

        #pragma unroll
        for (int mf = 0; mf < 8; ++mf)
            #pragma unroll
            for (int r = 0; r < 4; ++r)
                s_part[mf * 4 + r] += __builtin_amdgcn_exp2f(acc[mf][r]);
    }

    // reduce across the 16 col-lanes (n) sharing the same quad
    #pragma unroll
    for (int d = 1; d < 16; d <<= 1)
        #pragma unroll
        for (int i = 0; i < 32; ++i)
            s_part[i] += __shfl_xor(s_part[i], d, 64);

    if (col == 0) {
        #pragma unroll
        for (int i = 0; i < 32; ++i) {
            int row = mg * 128 + (i >> 2) * 16 + quad * 4 + (i & 3);
            atomicAdd(&S[row], s_part[i]);
        }
    }
    #undef STAGE
}

// ---- Kernel 3: pos logit + weighted mean ------------------------------------
__global__ void finalize_k(const unsigned short* __restrict__ featb,
                           const float* __restrict__ mem,
                           const int* __restrict__ labels,
                           const float* __restrict__ S,
                           float* __restrict__ out) {
    const int wave = threadIdx.x >> 6;
    const int lane = threadIdx.x & 63;
    const int b = blockIdx.x * 4 + wave;          // 256 blocks x 4 waves = 1024
    const int lab = labels[b];
    const float* mrow = mem + (size_t)lab * (4096 * 128);   // memory[lab][0][:]
    float fa = bf2f(featb[b * 128 + lane]);
    float fc = bf2f(featb[b * 128 + lane + 64]);
    float p = fa * mrow[lane] + fc * mrow[lane + 64];       // t_pos (log2 domain)
    #pragma unroll
    for (int m = 1; m < 64; m <<= 1) p += __shfl_xor(p, m, 64);
    if (lane == 0) {
        float w = (lab < 2) ? 1.3f : 1.0f;
        float v = w * LN2f * (log2f(S[b]) - p) * (1.0f / 1024.0f);
        atomicAdd(out, v);
    }
}

extern "C" void kernel_launch(void* const* d_in, const int* in_sizes, int n_in,
                              void* d_out, int out_size, void* d_ws, size_t ws_size,
                              hipStream_t stream) {
    const float* features = (const float*)d_in[0];
    const int*   labels   = (const int*)d_in[1];
    const float* memory   = (const float*)d_in[2];
    float* out = (float*)d_out;

    unsigned short* featb = (unsigned short*)d_ws;               // 256 KiB
    float* S = (float*)((char*)d_ws + 1024 * 128 * 2);           // 1024 floats

    normalize_feat<<<1024, 128, 0, stream>>>(features, featb, S, out);
    gemm_lse<<<dim3(64, 8), 256, 0, stream>>>(featb, memory, S);
    finalize_k<<<256, 256, 0, stream>>>(featb, memory, labels, S, out);
}

// Round 8
// 228.520 us; speedup vs baseline: 1.5153x; 1.1476x over previous
//
#include <hip/hip_runtime.h>

// MemoryBank contrastive loss, steady state.
// B=1024, D=128, C=50, K=4096, N = C*K = 204800. TEMP=0.3.
// loss = (1/B) * sum_b w_b * ( ln(sum exp(dot/T)) - dot_pos/T )
// SCALE = log2(e)/T folded into normalized bf16 features: MFMA acc feeds exp2.
//
// R8: kill the B-replication (R5/R7 were L3-request-bandwidth-bound:
// dur ~= replication x 105 MB / ~5.5 TB/s).
//  - ONE block covers ALL of M: 8 waves x 128 m-rows each (afrag 128 regs/wave,
//    compiler banks to AGPRs). Each block owns a private contiguous 800-row
//    n-slice -> every memory row read EXACTLY ONCE chip-wide (105 MB stream).
//  - B tile (32 rows, 16 KB fp32) staged via fully-coalesced global_load_lds:
//    16 instrs x 1 KB contiguous; inter-instr pad 16 B makes fragment reads
//    land 8 lanes per bank-quad (same structure as lane-linear b128) = clean.
//  - One barrier per tile, 1241 cyc MFMA per wave per tile; DMA for tile t+1
//    issued before COMPUTE(t) -> barrier drain waits on ~2500-cyc-old loads.

#define LN2f 0.6931471805599453f
#define SCALEf 4.808983469629878f   // log2(e)/0.3
#define NTILES 25                   // 32-row tiles per block (25*32 = 800 rows)
#define TPAD 1040                   // 1024 B DMA block + 16 B pad
#define TILE_LDS (16 * TPAD)        // 16640 B per buffer

typedef __attribute__((ext_vector_type(8))) short bf16x8;
typedef __attribute__((ext_vector_type(4))) float f32x4;
typedef unsigned int u32;

__device__ __forceinline__ unsigned short f2bf(float x) {
    union { float f; unsigned int u; } c; c.f = x;
    unsigned int u = c.u;
    u = (u + 0x7fffu + ((u >> 16) & 1u)) >> 16;   // RNE (features only)
    return (unsigned short)u;
}
__device__ __forceinline__ float bf2f(unsigned short h) {
    union { unsigned int u; float f; } c; c.u = ((unsigned int)h) << 16;
    return c.f;
}
// two fp32 -> two bf16 (truncation) in one v_perm_b32: [bf(lo) | bf(hi)<<16]
__device__ __forceinline__ unsigned int pack_bf2(float lo, float hi) {
    union { float f; unsigned int u; } a, b; a.f = lo; b.f = hi;
    return __builtin_amdgcn_perm(b.u, a.u, 0x07060302u);
}
// async DMA global -> LDS; gp per-lane (lane*16 included), lp wave-uniform base
__device__ __forceinline__ void gl_lds16(const void* gp, void* lp) {
    __builtin_amdgcn_global_load_lds(
        (const __attribute__((address_space(1))) u32*)gp,
        (__attribute__((address_space(3))) u32*)lp, 16, 0, 0);
}

// ---- Kernel 1: normalize+scale features -> bf16; zero S and out -------------
__global__ void normalize_feat(const float* __restrict__ f,
                               unsigned short* __restrict__ featb,
                               float* __restrict__ S,
                               float* __restrict__ out) {
    const int b = blockIdx.x;          // 1024 blocks
    const int t = threadIdx.x;         // 128 threads
    if (t == 0) S[b] = 0.0f;
    if (b == 0 && t == 1) *out = 0.0f;
    float v = f[b * 128 + t];
    float ss = v * v;
    #pragma unroll
    for (int m = 1; m < 64; m <<= 1) ss += __shfl_xor(ss, m, 64);
    __shared__ float wsum[2];
    if ((t & 63) == 0) wsum[t >> 6] = ss;
    __syncthreads();
    float tot = wsum[0] + wsum[1];
    float inv = SCALEf / fmaxf(sqrtf(tot), 1e-12f);
    featb[b * 128 + t] = f2bf(v * inv);
}

// ---- Kernel 2: fused GEMM + exp2-sum, full-M blocks -------------------------
// 512 thr = 8 waves; wave w owns m-rows [w*128, w*128+128) (mf=8).
// Block n-slice: rows [blockIdx.x*800, +800), 25 tiles of 32 rows.
__global__ __launch_bounds__(512, 2) void gemm_lse(
        const unsigned short* __restrict__ featb,  // [1024][128] bf16 (scaled)
        const float* __restrict__ mem,             // [204800][128] fp32
        float* __restrict__ S)                     // [1024] exp2-sums
{
    __shared__ __align__(16) char ldsb[2][TILE_LDS];

    const int tid  = threadIdx.x;
    const int wave = tid >> 6;        // 0..7
    const int lane = tid & 63;
    const int col  = lane & 15;
    const int quad = lane >> 4;

    // A fragments: A[m=col][k=quad*8+j], mf=8 x ks=4 (128 regs -> AGPR bank)
    bf16x8 afrag[8][4];
    #pragma unroll
    for (int mf = 0; mf < 8; ++mf)
        #pragma unroll
        for (int ks = 0; ks < 4; ++ks)
            afrag[mf][ks] = *(const bf16x8*)&featb[(size_t)(wave * 128 + mf * 16 + col) * 128
                                                   + ks * 32 + quad * 8];

    float s_part[32];
    #pragma unroll
    for (int i = 0; i < 32; ++i) s_part[i] = 0.0f;

    const char* memb = (const char*)mem + (size_t)blockIdx.x * 800 * 512;

    // DMA: tile = 32 rows x 512 B = 16 KB = 16 contiguous 1 KB instrs;
    // instr j (rows 2j,2j+1) -> LDS base j*TPAD. Wave w issues j = 2w, 2w+1.
    #define STAGE(bi, t_) {                                                     \
        const char* gt = memb + (size_t)(t_) * 16384;                           \
        _Pragma("unroll")                                                       \
        for (int jj = 0; jj < 2; ++jj) {                                        \
            int j = wave * 2 + jj;                                              \
            gl_lds16(gt + j * 1024 + lane * 16, &ldsb[bi][j * TPAD]);           \
        } }

    // fragment read: row r=nf*16+col granule g at (r>>1)*TPAD+(r&1)*512+g*16;
    // bank-quad = ((col>>1)+2*quad+h) mod 8 -> 8 lanes/quad-group = clean.
    #define COMPUTE(bi) {                                                       \
        const char* buf = &ldsb[bi][0];                                         \
        _Pragma("unroll")                                                       \
        for (int nf = 0; nf < 2; ++nf) {                                        \
            const char* rb = buf + (nf * 8 + (col >> 1)) * TPAD + (col & 1) * 512; \
            f32x4 acc[8];                                                       \
            _Pragma("unroll")                                                   \
            for (int mf = 0; mf < 8; ++mf) acc[mf] = (f32x4)(0.0f);             \
            _Pragma("unroll")                                                   \
            for (int ks = 0; ks < 4; ++ks) {                                    \
                const char* p = rb + (ks * 8 + quad * 2) * 16;                  \
                float4 f0 = *(const float4*)p;                                  \
                float4 f1 = *(const float4*)(p + 16);                           \
                uint4 pk;                                                       \
                pk.x = pack_bf2(f0.x, f0.y); pk.y = pack_bf2(f0.z, f0.w);       \
                pk.z = pack_bf2(f1.x, f1.y); pk.w = pack_bf2(f1.z, f1.w);       \
                bf16x8 bfrag = *(bf16x8*)&pk;                                   \
                _Pragma("unroll")                                               \
                for (int mf = 0; mf < 8; ++mf)                                  \
                    acc[mf] = __builtin_amdgcn_mfma_f32_16x16x32_bf16(          \
                        afrag[mf][ks], bfrag, acc[mf], 0, 0, 0);                \
            }                                                                   \
            _Pragma("unroll")                                                   \
            for (int mf = 0; mf < 8; ++mf)                                      \
                _Pragma("unroll")                                               \
                for (int r = 0; r < 4; ++r)                                     \
                    s_part[mf * 4 + r] += __builtin_amdgcn_exp2f(acc[mf][r]);   \
        } }

    STAGE(0, 0)
    __syncthreads();

    for (int t = 0; t < NTILES; ++t) {
        if (t + 1 < NTILES) STAGE((t + 1) & 1, t + 1)   // in flight during compute
        COMPUTE(t & 1)
        __syncthreads();   // drains t+1's DMA (issued one compute phase ago)
    }

    // reduce across the 16 col-lanes (n) sharing the same quad
    #pragma unroll
    for (int d = 1; d < 16; d <<= 1)
        #pragma unroll
        for (int i = 0; i < 32; ++i)
            s_part[i] += __shfl_xor(s_part[i], d, 64);

    if (col == 0) {
        #pragma unroll
        for (int i = 0; i < 32; ++i) {
            int row = wave * 128 + (i >> 2) * 16 + quad * 4 + (i & 3);
            atomicAdd(&S[row], s_part[i]);
        }
    }
    #undef STAGE
    #undef COMPUTE
}

// ---- Kernel 3: pos logit + weighted mean ------------------------------------
__global__ void finalize_k(const unsigned short* __restrict__ featb,
                           const float* __restrict__ mem,
                           const int* __restrict__ labels,
                           const float* __restrict__ S,
                           float* __restrict__ out) {
    const int wave = threadIdx.x >> 6;
    const int lane = threadIdx.x & 63;
    const int b = blockIdx.x * 4 + wave;          // 256 blocks x 4 waves = 1024
    const int lab = labels[b];
    const float* mrow = mem + (size_t)lab * (4096 * 128);   // memory[lab][0][:]
    float fa = bf2f(featb[b * 128 + lane]);
    float fc = bf2f(featb[b * 128 + lane + 64]);
    float p = fa * mrow[lane] + fc * mrow[lane + 64];       // t_pos (log2 domain)
    #pragma unroll
    for (int m = 1; m < 64; m <<= 1) p += __shfl_xor(p, m, 64);
    if (lane == 0) {
        float w = (lab < 2) ? 1.3f : 1.0f;
        float v = w * LN2f * (log2f(S[b]) - p) * (1.0f / 1024.0f);
        atomicAdd(out, v);
    }
}

extern "C" void kernel_launch(void* const* d_in, const int* in_sizes, int n_in,
                              void* d_out, int out_size, void* d_ws, size_t ws_size,
                              hipStream_t stream) {
    const float* features = (const float*)d_in[0];
    const int*   labels   = (const int*)d_in[1];
    const float* memory   = (const float*)d_in[2];
    float* out = (float*)d_out;

    unsigned short* featb = (unsigned short*)d_ws;               // 256 KiB
    float* S = (float*)((char*)d_ws + 1024 * 128 * 2);           // 1024 floats

    normalize_feat<<<1024, 128, 0, stream>>>(features, featb, S, out);
    gemm_lse<<<256, 512, 0, stream>>>(featb, memory, S);
    finalize_k<<<256, 256, 0, stream>>>(featb, memory, labels, S, out);
}